// Round 5
// baseline (7694.411 us; speedup 1.0000x reference)
//
#include <hip/hip_runtime.h>
#include <hip/hip_bf16.h>

// GRU-scan model, MI355X. Strategy:
//  k1_prep : cvt weights to bf16, fold biases, init h/acc/ctr buffers (in ws)
//  k2_xi   : xi[t][rg][cg][16][192] = x@W_ih^T + bias fold   (bf16, tiled MFMA)
//  k2_tio  : tio[t][rg][cg][16][16] = silu(x@Wt^T+bt)@Wo^T+bo (bf16, 2-stage)
//  k3_rec  : persistent recurrence v6: 64 rowgroups x 16 REAL batch rows, each
//            split across 4 sibling blocks by h-col quarter (kills the 4x
//            M-padding waste: 28 MFMAs/SIMD/step = 543cy floor). Siblings
//            exchange h slices (2KB) per step via L2 with per-sibling
//            release/acquire counters (agent scope, cross-XCD correct).
//            wf = 96 regs (trivially resident); gating fully in-register.
//  k4_out  : out = acc / 512
// T processed in chunks sized from ws_size (deterministic given ws_size).

typedef __attribute__((ext_vector_type(8))) __bf16 bf16x8;
typedef __attribute__((ext_vector_type(4))) __bf16 bf16x4;
typedef __attribute__((ext_vector_type(2))) __bf16 bf16x2;
typedef __attribute__((ext_vector_type(4))) float f32x4;

#define MFMA(a, b, c) __builtin_amdgcn_mfma_f32_16x16x32_bf16(a, b, c, 0, 0, 0)

__device__ __forceinline__ float fsig(float v) {
  float e = __builtin_amdgcn_exp2f(v * -1.442695041f);
  return __builtin_amdgcn_rcpf(1.0f + e);
}
__device__ __forceinline__ float ftanh(float v) {
  float e = __builtin_amdgcn_exp2f(v * 2.885390082f);
  return 1.0f - 2.0f * __builtin_amdgcn_rcpf(1.0f + e);
}

// ---- workspace layout (bytes) ----
#define O_WIN 0u         // [1024][128] bf16  (W_ih rows 0-767, Wt rows 768-1023)
#define O_WHH 262144u    // [768][256] bf16
#define O_WO  655360u    // [64][256] bf16
#define O_WG  688128u    // [64][256] bf16
#define O_B1  720896u    // [1024] f32 folded bias
#define O_H   724992u    // [1024][256] f32 h state (fp32 master)
#define O_ACC 1773568u   // [1024][64] f32 output accumulator
#define O_HX  2035712u   // [2 slot][64 rg][4 cg][16][64] bf16 = 1 MiB exchange
#define O_CTR 3084288u   // [64 rg][16] u32 (4 used per rg) = 4 KiB
#define O_TIO 3088384u   // [TC][64][4][16][16] bf16, then xi [TC][64][4][16][192] bf16

__global__ void k1_prep(const float* __restrict__ Wih, const float* __restrict__ Wt,
                        const float* __restrict__ Whh, const float* __restrict__ Wo,
                        const float* __restrict__ Wg, const float* __restrict__ bih,
                        const float* __restrict__ bhh, const float* __restrict__ bt,
                        const float* __restrict__ h0, char* __restrict__ ws) {
  unsigned n = blockIdx.x * 256u + threadIdx.x;
  __bf16* win = (__bf16*)(ws + O_WIN);
  __bf16* whh = (__bf16*)(ws + O_WHH);
  __bf16* wo = (__bf16*)(ws + O_WO);
  __bf16* wg = (__bf16*)(ws + O_WG);
  float* b1 = (float*)(ws + O_B1);
  float* hb = (float*)(ws + O_H);
  float* ac = (float*)(ws + O_ACC);
  unsigned* ct = (unsigned*)(ws + O_CTR);
  if (n < 98304u) win[n] = (__bf16)Wih[n];
  else if (n < 131072u) { unsigned i = n - 98304u; win[98304u + i] = (__bf16)Wt[i]; }
  else if (n < 327680u) { unsigned i = n - 131072u; whh[i] = (__bf16)Whh[i]; }
  else if (n < 344064u) { unsigned i = n - 327680u; wo[i] = (__bf16)Wo[i]; }
  else if (n < 360448u) { unsigned i = n - 344064u; wg[i] = (__bf16)Wg[i]; }
  else if (n < 361472u) {
    unsigned i = n - 360448u;
    float v = (i < 512u) ? (bih[i] + bhh[i]) : ((i < 768u) ? bih[i] : bt[i - 768u]);
    b1[i] = v;
  } else if (n < 623616u) { unsigned i = n - 361472u; hb[i] = h0[i]; }
  else if (n < 689152u) { unsigned i = n - 623616u; ac[i] = 0.0f; }
  else if (n < 690176u) { unsigned i = n - 689152u; ct[i] = 0u; }
}

// ---------------- k2_xi: xi = x @ W_ih^T + bias1 (cols 0..767) ----------------
__global__ __launch_bounds__(256, 2) void k2_xi(
    const float* __restrict__ x, const __bf16* __restrict__ win,
    const float* __restrict__ b1, __bf16* __restrict__ xi, int t0, int tcbits) {
  extern __shared__ char sm2[];
  __bf16* Asm = (__bf16*)sm2;            // [128][136] bf16
  __bf16* Bsm = (__bf16*)(sm2 + 34816);  // [128][136]
  const int tid = threadIdx.x;
  const int lane = tid & 63, wv = tid >> 6;
  const int m0 = blockIdx.x * 128;
  const int tcm = (1 << tcbits) - 1;
#pragma unroll
  for (int rnd = 0; rnd < 16; ++rnd) {
    int row = rnd * 8 + (tid >> 5);
    int cr = m0 + row;
    int bb = cr >> tcbits, tt = cr & tcm;
    const float* xr = x + ((size_t)bb * 512 + (size_t)(t0 + tt)) * 128 + (tid & 31) * 4;
    float4 v = *(const float4*)xr;
    bf16x4 b4 = {(__bf16)v.x, (__bf16)v.y, (__bf16)v.z, (__bf16)v.w};
    *(bf16x4*)&Asm[row * 136 + (tid & 31) * 4] = b4;
  }
  for (int nc = 0; nc < 6; ++nc) {
    __syncthreads();
#pragma unroll
    for (int rnd = 0; rnd < 8; ++rnd) {
      int rr = rnd * 16 + (tid >> 4);
      uint4 w4 = *(const uint4*)(win + (size_t)(nc * 128 + rr) * 128 + (tid & 15) * 8);
      *(uint4*)&Bsm[rr * 136 + (tid & 15) * 8] = w4;
    }
    __syncthreads();
    f32x4 zv = {0.f, 0.f, 0.f, 0.f};
    f32x4 acc[2][8];
#pragma unroll
    for (int mi = 0; mi < 2; ++mi)
#pragma unroll
      for (int nt = 0; nt < 8; ++nt) acc[mi][nt] = zv;
#pragma unroll
    for (int kt = 0; kt < 4; ++kt) {
      bf16x8 a0 = *(const bf16x8*)&Asm[(wv * 32 + (lane & 15)) * 136 + kt * 32 + (lane >> 4) * 8];
      bf16x8 a1 = *(const bf16x8*)&Asm[(wv * 32 + 16 + (lane & 15)) * 136 + kt * 32 + (lane >> 4) * 8];
#pragma unroll
      for (int nt = 0; nt < 8; ++nt) {
        bf16x8 b = *(const bf16x8*)&Bsm[(nt * 16 + (lane & 15)) * 136 + kt * 32 + (lane >> 4) * 8];
        acc[0][nt] = MFMA(a0, b, acc[0][nt]);
        acc[1][nt] = MFMA(a1, b, acc[1][nt]);
      }
    }
    __syncthreads();  // done reading Bsm; reuse as store staging
#pragma unroll
    for (int nt = 0; nt < 8; ++nt) {
      float bv = b1[nc * 128 + nt * 16 + (lane & 15)];
#pragma unroll
      for (int mi = 0; mi < 2; ++mi)
#pragma unroll
        for (int r = 0; r < 4; ++r) {
          int rowb = wv * 32 + mi * 16 + (lane >> 4) * 4 + r;
          Bsm[rowb * 136 + nt * 16 + (lane & 15)] = (__bf16)(acc[mi][nt][r] + bv);
        }
    }
    __syncthreads();
#pragma unroll
    for (int rnd = 0; rnd < 8; ++rnd) {
      int row = rnd * 16 + (tid >> 4);
      int cr = m0 + row;
      int bb = cr >> tcbits, tt = cr & tcm;
      uint4 v = *(const uint4*)&Bsm[row * 136 + (tid & 15) * 8];
      int col = nc * 128 + (tid & 15) * 8;
      int g = col >> 8, gc = col & 255;
      size_t dst = ((((size_t)tt * 64 + (bb >> 4)) * 4 + (gc >> 6)) * 16 + (bb & 15)) * 192
                   + g * 64 + (gc & 63);
      *(uint4*)(xi + dst) = v;
    }
  }
}

// -------- k2_tio: tio = silu(x@Wt^T + bt) @ Wo^T + bo --------
__global__ __launch_bounds__(256, 1) void k2_tio(
    const float* __restrict__ x, const __bf16* __restrict__ win,
    const __bf16* __restrict__ wo, const float* __restrict__ b1,
    const float* __restrict__ bo, __bf16* __restrict__ tio, int t0, int tcbits) {
  extern __shared__ char sm3[];
  __bf16* Asm = (__bf16*)sm3;             // [128][136]
  __bf16* Bsm = (__bf16*)(sm3 + 34816);   // [128][136] then [64][264]
  __bf16* Ti = (__bf16*)(sm3 + 69632);    // [128][264]
  const int tid = threadIdx.x;
  const int lane = tid & 63, wv = tid >> 6;
  const int m0 = blockIdx.x * 128;
  const int tcm = (1 << tcbits) - 1;
#pragma unroll
  for (int rnd = 0; rnd < 16; ++rnd) {
    int row = rnd * 8 + (tid >> 5);
    int cr = m0 + row;
    int bb = cr >> tcbits, tt = cr & tcm;
    const float* xr = x + ((size_t)bb * 512 + (size_t)(t0 + tt)) * 128 + (tid & 31) * 4;
    float4 v = *(const float4*)xr;
    bf16x4 b4 = {(__bf16)v.x, (__bf16)v.y, (__bf16)v.z, (__bf16)v.w};
    *(bf16x4*)&Asm[row * 136 + (tid & 31) * 4] = b4;
  }
  for (int nc = 0; nc < 2; ++nc) {
    __syncthreads();
#pragma unroll
    for (int rnd = 0; rnd < 8; ++rnd) {
      int rr = rnd * 16 + (tid >> 4);
      uint4 w4 = *(const uint4*)(win + (size_t)(98304 / 128 + nc * 128 + rr) * 128 + (tid & 15) * 8);
      *(uint4*)&Bsm[rr * 136 + (tid & 15) * 8] = w4;
    }
    __syncthreads();
    f32x4 zv = {0.f, 0.f, 0.f, 0.f};
    f32x4 acc[2][8];
#pragma unroll
    for (int mi = 0; mi < 2; ++mi)
#pragma unroll
      for (int nt = 0; nt < 8; ++nt) acc[mi][nt] = zv;
#pragma unroll
    for (int kt = 0; kt < 4; ++kt) {
      bf16x8 a0 = *(const bf16x8*)&Asm[(wv * 32 + (lane & 15)) * 136 + kt * 32 + (lane >> 4) * 8];
      bf16x8 a1 = *(const bf16x8*)&Asm[(wv * 32 + 16 + (lane & 15)) * 136 + kt * 32 + (lane >> 4) * 8];
#pragma unroll
      for (int nt = 0; nt < 8; ++nt) {
        bf16x8 b = *(const bf16x8*)&Bsm[(nt * 16 + (lane & 15)) * 136 + kt * 32 + (lane >> 4) * 8];
        acc[0][nt] = MFMA(a0, b, acc[0][nt]);
        acc[1][nt] = MFMA(a1, b, acc[1][nt]);
      }
    }
#pragma unroll
    for (int nt = 0; nt < 8; ++nt) {
      float bv = b1[768 + nc * 128 + nt * 16 + (lane & 15)];
#pragma unroll
      for (int mi = 0; mi < 2; ++mi)
#pragma unroll
        for (int r = 0; r < 4; ++r) {
          int rowb = wv * 32 + mi * 16 + (lane >> 4) * 4 + r;
          float s = acc[mi][nt][r] + bv;
          s = s * __builtin_amdgcn_rcpf(1.0f + __builtin_amdgcn_exp2f(s * -1.442695041f));
          Ti[rowb * 264 + nc * 128 + nt * 16 + (lane & 15)] = (__bf16)s;
        }
    }
  }
  __syncthreads();
  for (int i = tid; i < 2048; i += 256) {
    int row = i >> 5;
    int c8 = (i & 31) * 8;
    *(uint4*)&Bsm[row * 264 + c8] = *(const uint4*)(wo + row * 256 + c8);
  }
  __syncthreads();
  f32x4 zv = {0.f, 0.f, 0.f, 0.f};
  f32x4 acc2[2][4];
#pragma unroll
  for (int mi = 0; mi < 2; ++mi)
#pragma unroll
    for (int nt = 0; nt < 4; ++nt) acc2[mi][nt] = zv;
#pragma unroll
  for (int kt = 0; kt < 8; ++kt) {
    bf16x8 a0 = *(const bf16x8*)&Ti[(wv * 32 + (lane & 15)) * 264 + kt * 32 + (lane >> 4) * 8];
    bf16x8 a1 = *(const bf16x8*)&Ti[(wv * 32 + 16 + (lane & 15)) * 264 + kt * 32 + (lane >> 4) * 8];
#pragma unroll
    for (int nt = 0; nt < 4; ++nt) {
      bf16x8 b = *(const bf16x8*)&Bsm[(nt * 16 + (lane & 15)) * 264 + kt * 32 + (lane >> 4) * 8];
      acc2[0][nt] = MFMA(a0, b, acc2[0][nt]);
      acc2[1][nt] = MFMA(a1, b, acc2[1][nt]);
    }
  }
#pragma unroll
  for (int nt = 0; nt < 4; ++nt) {
    int col = nt * 16 + (lane & 15);
    float bv = bo[col];
#pragma unroll
    for (int mi = 0; mi < 2; ++mi)
#pragma unroll
      for (int r = 0; r < 4; ++r) {
        int rowb = wv * 32 + mi * 16 + (lane >> 4) * 4 + r;
        int cr = m0 + rowb;
        int bb = cr >> tcbits, tt = cr & tcm;
        size_t dst = ((((size_t)tt * 64 + (bb >> 4)) * 4 + (col >> 4)) * 16 + (bb & 15)) * 16
                     + (col & 15);
        tio[dst] = (__bf16)(acc2[mi][nt][r] + bv);
      }
  }
}

// ---------------- k3_rec v6: 16-row rowgroups, 4-block h exchange ----------------
// 256 blocks x 256 thr (4 waves = 1/SIMD). Block (rg = bid&63, cg = bid>>6):
// batch rows [16rg,+16), h-cols [64cg,+64). Wave wv owns hcol subtile
// [64cg+16wv,+16) x 3 gates: wf[3][8] = 96 regs. Swapped MFMA(W, h):
// D thread (l15=batch, lg*4+r = hcol) -> gating fully in-register.
// proj: block owns out-cols [16cg,+16); wave wv does kt-pair {2wv,2wv+1}
// partials -> pjb (LDS, double-buffered), combined post-barrier.
// h(s) slices published to hx[s&1] via agent atomics; per-sibling counters
// ctr[rg][cg] (release-store s+1 / acquire-spin >= s) gate each step.
// LDS: hb[2][16][264] bf16 = 16896 @0 ; pjb[2][8][16][16] f32 = 16384 @16896
__global__ __launch_bounds__(256, 1) void k3_rec(
    const __bf16* __restrict__ xi, const __bf16* __restrict__ tio,
    const __bf16* __restrict__ whh, const __bf16* __restrict__ wo,
    const __bf16* __restrict__ wg, const float* __restrict__ bhn,
    const float* __restrict__ bg, float* __restrict__ hbufg,
    float* __restrict__ accb, __bf16* __restrict__ hx,
    unsigned* __restrict__ ctr, int TC, int t0) {
  extern __shared__ char sm[];
  __bf16* hb = (__bf16*)sm;           // [2][16][264] bf16
  float* pjb = (float*)(sm + 16896);  // [2][8][16][16] f32
  const int tid = threadIdx.x;
  const int lane = tid & 63, wv = tid >> 6;
  const int l15 = lane & 15, lg = lane >> 4;
  const int rg = blockIdx.x & 63, cg = blockIdx.x >> 6;
  unsigned* myctr = ctr + rg * 16;

  // register-resident weights (small now; demotion risk gone)
  bf16x8 wf[3][8];
#pragma unroll
  for (int g = 0; g < 3; ++g)
#pragma unroll
    for (int kt = 0; kt < 8; ++kt)
      wf[g][kt] = *(const bf16x8*)(whh + (size_t)(g * 256 + cg * 64 + wv * 16 + l15) * 256
                                   + kt * 32 + lg * 8);
  bf16x8 wpo[2], wpg[2];
#pragma unroll
  for (int j = 0; j < 2; ++j) {
    wpo[j] = *(const bf16x8*)(wo + (size_t)(cg * 16 + l15) * 256 + (2 * wv + j) * 32 + lg * 8);
    wpg[j] = *(const bf16x8*)(wg + (size_t)(cg * 16 + l15) * 256 + (2 * wv + j) * 32 + lg * 8);
  }
  const int hcol = cg * 64 + wv * 16 + lg * 4;  // first of thread's 4 h-cols
  float bhnp[4];
#pragma unroll
  for (int r = 0; r < 4; ++r) bhnp[r] = bhn[hcol + r];
  const int cb = tid >> 4, cc = tid & 15;  // combine/oacc mapping (row cb, ocol cc)
  const float bgv = bg[cg * 16 + cc];
  float oacc = accb[((size_t)rg * 16 + cb) * 64 + cg * 16 + cc];

  // fp32 master h (batch l15, cols hcol..hcol+3)
  float hreg[4];
  {
    const float* hp = hbufg + ((size_t)rg * 16 + l15) * 256 + hcol;
#pragma unroll
    for (int r = 0; r < 4; ++r) hreg[r] = hp[r];
  }
  if (t0 == 0) {  // fill hb[0] with h0 (full 16x256)
#pragma unroll
    for (int j = 0; j < 4; ++j) {
      f32x4 v = *(const f32x4*)(hbufg + ((size_t)rg * 16 + cb) * 256 + cc * 16 + j * 4);
      bf16x4 b4 = {(__bf16)v[0], (__bf16)v[1], (__bf16)v[2], (__bf16)v[3]};
      *(bf16x4*)&hb[cb * 264 + cc * 16 + j * 4] = b4;
    }
  }
  // prologue prefetch xi(0)
  bf16x4 xiN[3];
  {
    const __bf16* xs = xi + ((size_t)rg * 4 + cg) * 3072;
#pragma unroll
    for (int g = 0; g < 3; ++g)
      xiN[g] = *(const bf16x4*)(xs + l15 * 192 + g * 64 + wv * 16 + lg * 4);
  }
  float tioB = 0.f;
  __syncthreads();

#pragma unroll 1
  for (int t = 0; t < TC; ++t) {
    const int s = t0 + t;
    const int cur = t & 1, nxt = cur ^ 1;
    if (s > 0) {
      if (tid == 0) {
#pragma unroll
        for (int q = 0; q < 4; ++q) {
          if (q == cg) continue;
          while (__hip_atomic_load(&myctr[q], __ATOMIC_RELAXED, __HIP_MEMORY_SCOPE_AGENT)
                 < (unsigned)s)
            __builtin_amdgcn_s_sleep(2);
        }
#pragma unroll
        for (int q = 0; q < 4; ++q)
          if (q != cg)
            (void)__hip_atomic_load(&myctr[q], __ATOMIC_ACQUIRE, __HIP_MEMORY_SCOPE_AGENT);
      }
      __syncthreads();
      const __bf16* hsl = hx + (size_t)((s - 1) & 1) * 262144;
#pragma unroll
      for (int c4 = 0; c4 < 4; ++c4) {
        unsigned long long v = __hip_atomic_load(
            (unsigned long long*)(hsl + ((size_t)rg * 4 + c4) * 1024 + cb * 64 + cc * 4),
            __ATOMIC_RELAXED, __HIP_MEMORY_SCOPE_AGENT);
        *(unsigned long long*)&hb[cur * 4224 + cb * 264 + c4 * 64 + cc * 4] = v;
      }
    }
    // shift xi regs; issue next prefetch + tio(t) load (latency hides under MFMA)
    bf16x4 xiC[3];
#pragma unroll
    for (int g = 0; g < 3; ++g) xiC[g] = xiN[g];
    {
      int tn = (t + 1 < TC) ? t + 1 : t;
      const __bf16* xs = xi + (((size_t)tn * 64 + rg) * 4 + cg) * 3072;
#pragma unroll
      for (int g = 0; g < 3; ++g)
        xiN[g] = *(const bf16x4*)(xs + l15 * 192 + g * 64 + wv * 16 + lg * 4);
    }
    float tioC = (float)tio[(((size_t)t * 64 + rg) * 4 + cg) * 256 + cb * 16 + cc];
    __syncthreads();  // BAR-A: hb[cur] complete
    bf16x8 afr[8];
#pragma unroll
    for (int kt = 0; kt < 8; ++kt)
      afr[kt] = *(const bf16x8*)&hb[cur * 4224 + l15 * 264 + kt * 32 + lg * 8];
    // hh: 3 gate accumulator chains (ILP) over K=256
    f32x4 ar = {0.f, 0.f, 0.f, 0.f}, az = {0.f, 0.f, 0.f, 0.f}, an = {0.f, 0.f, 0.f, 0.f};
#pragma unroll
    for (int kt = 0; kt < 8; ++kt) {
      ar = MFMA(wf[0][kt], afr[kt], ar);
      az = MFMA(wf[1][kt], afr[kt], az);
      an = MFMA(wf[2][kt], afr[kt], an);
    }
    // proj K-partials (kt-pair 2wv,2wv+1) on h(t-1)
    f32x4 po = {0.f, 0.f, 0.f, 0.f}, pg4 = {0.f, 0.f, 0.f, 0.f};
#pragma unroll
    for (int j = 0; j < 2; ++j) {
      po = MFMA(wpo[j], afr[2 * wv + j], po);
      pg4 = MFMA(wpg[j], afr[2 * wv + j], pg4);
    }
    *(f32x4*)&pjb[(cur * 8 + wv * 2 + 0) * 256 + l15 * 16 + lg * 4] = po;
    *(f32x4*)&pjb[(cur * 8 + wv * 2 + 1) * 256 + l15 * 16 + lg * 4] = pg4;
    // gating fully in-register
    {
#pragma unroll
      for (int r = 0; r < 4; ++r) {
        float r_ = fsig((float)xiC[0][r] + ar[r]);
        float z_ = fsig((float)xiC[1][r] + az[r]);
        float n_ = ftanh((float)xiC[2][r] + r_ * (an[r] + bhnp[r]));
        hreg[r] = n_ + z_ * (hreg[r] - n_);
      }
      bf16x4 h4 = {(__bf16)hreg[0], (__bf16)hreg[1], (__bf16)hreg[2], (__bf16)hreg[3]};
      *(bf16x4*)&hb[nxt * 4224 + l15 * 264 + hcol] = h4;
      unsigned long long uv;
      __builtin_memcpy(&uv, &h4, 8);
      __hip_atomic_store(
          (unsigned long long*)(hx + (size_t)(s & 1) * 262144 + ((size_t)rg * 4 + cg) * 1024
                                + l15 * 64 + wv * 16 + lg * 4),
          uv, __ATOMIC_RELAXED, __HIP_MEMORY_SCOPE_AGENT);
    }
    __syncthreads();  // BAR-B: drains hx stores (vmcnt0) + pjb/hb visible
    if (tid == 0)
      __hip_atomic_store(&myctr[cg], (unsigned)(s + 1), __ATOMIC_RELEASE,
                         __HIP_MEMORY_SCOPE_AGENT);
    // combine output(t-1) = (proj_o(h(t-1)) + tio(t-1)) * sig(proj_g(h(t-1)) + bg)
    if (t >= 1) {
      float p_o = 0.f, p_g = bgv;
#pragma unroll
      for (int w2 = 0; w2 < 4; ++w2) {
        p_o += pjb[(cur * 8 + w2 * 2 + 0) * 256 + cb * 16 + cc];
        p_g += pjb[(cur * 8 + w2 * 2 + 1) * 256 + cb * 16 + cc];
      }
      oacc += (p_o + tioB) * fsig(p_g);
    }
    tioB = tioC;
  }
  // epilogue: output(t0+TC-1) needs proj of final h with full 256 cols
  {
    const int s = t0 + TC;
    const int cur = TC & 1;
    if (tid == 0) {
#pragma unroll
      for (int q = 0; q < 4; ++q) {
        if (q == cg) continue;
        while (__hip_atomic_load(&myctr[q], __ATOMIC_RELAXED, __HIP_MEMORY_SCOPE_AGENT)
               < (unsigned)s)
          __builtin_amdgcn_s_sleep(2);
      }
#pragma unroll
      for (int q = 0; q < 4; ++q)
        if (q != cg)
          (void)__hip_atomic_load(&myctr[q], __ATOMIC_ACQUIRE, __HIP_MEMORY_SCOPE_AGENT);
    }
    __syncthreads();
    const __bf16* hsl = hx + (size_t)((s - 1) & 1) * 262144;
#pragma unroll
    for (int c4 = 0; c4 < 4; ++c4) {
      unsigned long long v = __hip_atomic_load(
          (unsigned long long*)(hsl + ((size_t)rg * 4 + c4) * 1024 + cb * 64 + cc * 4),
          __ATOMIC_RELAXED, __HIP_MEMORY_SCOPE_AGENT);
      *(unsigned long long*)&hb[cur * 4224 + cb * 264 + c4 * 64 + cc * 4] = v;
    }
    __syncthreads();
    bf16x8 afr[8];
#pragma unroll
    for (int kt = 0; kt < 8; ++kt)
      afr[kt] = *(const bf16x8*)&hb[cur * 4224 + l15 * 264 + kt * 32 + lg * 8];
    f32x4 po = {0.f, 0.f, 0.f, 0.f}, pg4 = {0.f, 0.f, 0.f, 0.f};
#pragma unroll
    for (int j = 0; j < 2; ++j) {
      po = MFMA(wpo[j], afr[2 * wv + j], po);
      pg4 = MFMA(wpg[j], afr[2 * wv + j], pg4);
    }
    *(f32x4*)&pjb[(cur * 8 + wv * 2 + 0) * 256 + l15 * 16 + lg * 4] = po;
    *(f32x4*)&pjb[(cur * 8 + wv * 2 + 1) * 256 + l15 * 16 + lg * 4] = pg4;
    __syncthreads();
    float p_o = 0.f, p_g = bgv;
#pragma unroll
    for (int w2 = 0; w2 < 4; ++w2) {
      p_o += pjb[(cur * 8 + w2 * 2 + 0) * 256 + cb * 16 + cc];
      p_g += pjb[(cur * 8 + w2 * 2 + 1) * 256 + cb * 16 + cc];
    }
    oacc += (p_o + tioB) * fsig(p_g);
  }
  // writeback
  {
    float* hp = hbufg + ((size_t)rg * 16 + l15) * 256 + hcol;
#pragma unroll
    for (int r = 0; r < 4; ++r) hp[r] = hreg[r];
  }
  accb[((size_t)rg * 16 + cb) * 64 + cg * 16 + cc] = oacc;
}

__global__ void k4_out(const float* __restrict__ accb, float* __restrict__ out) {
  int i = blockIdx.x * 256 + threadIdx.x;
  out[i] = accb[i] * (1.0f / 512.0f);
}

extern "C" void kernel_launch(void* const* d_in, const int* in_sizes, int n_in,
                              void* d_out, int out_size, void* d_ws, size_t ws_size,
                              hipStream_t stream) {
  const float* x = (const float*)d_in[0];
  const float* h0 = (const float*)d_in[1];
  const float* Wih = (const float*)d_in[2];
  const float* bih = (const float*)d_in[3];
  const float* Whh = (const float*)d_in[4];
  const float* bhh = (const float*)d_in[5];
  const float* Wt = (const float*)d_in[6];
  const float* bt = (const float*)d_in[7];
  const float* Wo = (const float*)d_in[8];
  const float* bo = (const float*)d_in[9];
  const float* Wg = (const float*)d_in[10];
  const float* bg = (const float*)d_in[11];
  float* out = (float*)d_out;
  char* ws = (char*)d_ws;

  // pick largest power-of-2 time-chunk that fits ws
  int TC = 512;
  while (TC > 1 && (3088384ull + (size_t)TC * 1703936ull) > ws_size) TC >>= 1;
  int tcbits = 0;
  while ((1 << tcbits) != TC) ++tcbits;

  __bf16* win = (__bf16*)(ws + O_WIN);
  __bf16* whhb = (__bf16*)(ws + O_WHH);
  __bf16* wob = (__bf16*)(ws + O_WO);
  __bf16* wgb = (__bf16*)(ws + O_WG);
  float* b1 = (float*)(ws + O_B1);
  float* hbuf = (float*)(ws + O_H);
  float* accb = (float*)(ws + O_ACC);
  __bf16* hxb = (__bf16*)(ws + O_HX);
  unsigned* ctrb = (unsigned*)(ws + O_CTR);
  __bf16* tioc = (__bf16*)(ws + O_TIO);
  __bf16* xic = (__bf16*)(ws + O_TIO + (size_t)TC * 131072u);

  (void)hipFuncSetAttribute((const void*)k2_xi, hipFuncAttributeMaxDynamicSharedMemorySize, 69632);
  (void)hipFuncSetAttribute((const void*)k2_tio, hipFuncAttributeMaxDynamicSharedMemorySize, 137216);
  (void)hipFuncSetAttribute((const void*)k3_rec, hipFuncAttributeMaxDynamicSharedMemorySize, 33280);

  k1_prep<<<2696, 256, 0, stream>>>(Wih, Wt, Whh, Wo, Wg, bih, bhh, bt, h0, ws);
  int nch = 512 / TC;
  for (int c = 0; c < nch; ++c) {
    int t0 = c * TC;
    k2_xi<<<8 * TC, 256, 69632, stream>>>(x, win, b1, xic, t0, tcbits);
    k2_tio<<<8 * TC, 256, 137216, stream>>>(x, win, wob, b1, bo, tioc, t0, tcbits);
    k3_rec<<<256, 256, 33280, stream>>>(xic, tioc, whhb, wob, wgb, bhh + 512, bg, hbuf,
                                        accb, hxb, ctrb, TC, t0);
  }
  k4_out<<<256, 256, 0, stream>>>(accb, out);
}